// Round 10
// baseline (314.977 us; speedup 1.0000x reference)
//
#include <hip/hip_runtime.h>

// GraphConv x2, CSR-pull + f16 MFMA GEMMs (R10):
//   wcast/xcast -> f16 staging
//   CSR build: hist_rank (XCD-PARTITIONED 8-replica counters) ->
//              scan_p1 (fused replica-base + tile scan) -> scan_p2/p3 ->
//              atomic-free fill (replica id recomputed from blockIdx)
//   pull_h128 / mfma_gemm1 / mfma_gemm2 / pull_add_h64 unchanged from R9.
//
// R10 rationale: hist_rank stayed top (65 us) with WRITE_SIZE 56 MB vs 13 MB
// logical — ~780K line writebacks = cross-XCD ownership migration of counter
// lines (blocks round-robin across 8 XCDs, dst random -> 7/8 of atomics hit a
// line owned by another XCD's L2). Replicating the histogram per
// blockIdx&7 class keeps every atomic in one XCD's L2 slice (400 KB,
// L2-resident, no migration). Rank stays globally exact via per-replica
// exclusive bases computed in scan_p1 (in-place) and re-added in fill.

typedef float f4 __attribute__((ext_vector_type(4)));
typedef _Float16 h8 __attribute__((ext_vector_type(8)));
typedef _Float16 h2 __attribute__((ext_vector_type(2)));

#define NREP 8   // histogram replicas = XCD count (blockIdx & 7 classes)

__device__ __forceinline__ float2 h2f(unsigned u) {
    h2 p = __builtin_bit_cast(h2, u);
    float2 r; r.x = (float)p[0]; r.y = (float)p[1];
    return r;
}
__device__ __forceinline__ unsigned f2h(float a, float b) {
    h2 p; p[0] = (_Float16)a; p[1] = (_Float16)b;
    return __builtin_bit_cast(unsigned, p);
}

// ---------------------------- casts ----------------------------------------
// wbuf layout (halves): wr1h @0 [128x128] | wq1h @16384 | wr2h @32768 [64x128]
// | wq2h @40960  (total 49152)
__global__ void wcast(const float* __restrict__ wr1, const float* __restrict__ wq1,
                      const float* __restrict__ wr2, const float* __restrict__ wq2,
                      _Float16* __restrict__ wb)
{
    int i = blockIdx.x * 256 + threadIdx.x;
    if (i < 16384)      wb[i] = (_Float16)wr1[i];
    else if (i < 32768) wb[i] = (_Float16)wq1[i - 16384];
    else if (i < 40960) wb[i] = (_Float16)wr2[i - 32768];
    else if (i < 49152) wb[i] = (_Float16)wq2[i - 40960];
}

__global__ void xcast(const float* __restrict__ x, _Float16* __restrict__ xh,
                      long n)   // n = N*128, multiple of 8
{
    long i = (long)(blockIdx.x * 256 + threadIdx.x) * 8;
    if (i >= n) return;
    f4 a = *(const f4*)(x + i);
    f4 b = *(const f4*)(x + i + 4);
    h8 o;
    o[0] = (_Float16)a[0]; o[1] = (_Float16)a[1];
    o[2] = (_Float16)a[2]; o[3] = (_Float16)a[3];
    o[4] = (_Float16)b[0]; o[5] = (_Float16)b[1];
    o[6] = (_Float16)b[2]; o[7] = (_Float16)b[3];
    *(h8*)(xh + i) = o;
}

// ---------------------------- CSR build ------------------------------------
// histogram into this block's XCD-class replica + per-edge local rank
__global__ void hist_rank(const int* __restrict__ dst, int* __restrict__ cnt8,
                          int* __restrict__ rank, int E, int N)
{
    int e = blockIdx.x * 256 + threadIdx.x;
    if (e < E) {
        int r = blockIdx.x & (NREP - 1);
        rank[e] = atomicAdd(&cnt8[(size_t)r * N + dst[e]], 1);
    }
}

// fused: per-node replica exclusive bases (in-place) + total, then tile scan
__global__ __launch_bounds__(256) void scan_p1(int* __restrict__ cnt8,
                                               int* __restrict__ row_ptr,
                                               int* __restrict__ blk_sum, int N)
{
    __shared__ int ts[256];
    const int tid = threadIdx.x;
    const int i = blockIdx.x * 256 + tid;
    int v = 0;
    int base0, base1, base2, base3, base4, base5, base6, base7;
    if (i < N) {
        int c;
        c = cnt8[0 * (size_t)N + i]; base0 = v; v += c;
        c = cnt8[1 * (size_t)N + i]; base1 = v; v += c;
        c = cnt8[2 * (size_t)N + i]; base2 = v; v += c;
        c = cnt8[3 * (size_t)N + i]; base3 = v; v += c;
        c = cnt8[4 * (size_t)N + i]; base4 = v; v += c;
        c = cnt8[5 * (size_t)N + i]; base5 = v; v += c;
        c = cnt8[6 * (size_t)N + i]; base6 = v; v += c;
        c = cnt8[7 * (size_t)N + i]; base7 = v; v += c;
        cnt8[0 * (size_t)N + i] = base0;
        cnt8[1 * (size_t)N + i] = base1;
        cnt8[2 * (size_t)N + i] = base2;
        cnt8[3 * (size_t)N + i] = base3;
        cnt8[4 * (size_t)N + i] = base4;
        cnt8[5 * (size_t)N + i] = base5;
        cnt8[6 * (size_t)N + i] = base6;
        cnt8[7 * (size_t)N + i] = base7;
    }
    ts[tid] = v;
    __syncthreads();
#pragma unroll
    for (int off = 1; off < 256; off <<= 1) {
        int add = (tid >= off) ? ts[tid - off] : 0;
        __syncthreads();
        ts[tid] += add;
        __syncthreads();
    }
    if (i < N) row_ptr[i] = ts[tid] - v;          // exclusive within tile
    if (tid == 255) blk_sum[blockIdx.x] = ts[255];
}

__global__ __launch_bounds__(1024) void scan_p2(int* __restrict__ blk_sum, int nb)
{
    __shared__ int ts[1024];
    const int tid = threadIdx.x;
    int v = (tid < nb) ? blk_sum[tid] : 0;
    ts[tid] = v;
    __syncthreads();
#pragma unroll
    for (int off = 1; off < 1024; off <<= 1) {
        int add = (tid >= off) ? ts[tid - off] : 0;
        __syncthreads();
        ts[tid] += add;
        __syncthreads();
    }
    if (tid < nb) blk_sum[tid] = ts[tid] - v;
}

__global__ __launch_bounds__(256) void scan_p3(int* __restrict__ row_ptr,
                                               const int* __restrict__ blk_sum,
                                               int N, int E)
{
    const int i = blockIdx.x * 256 + threadIdx.x;
    if (i < N) row_ptr[i] += blk_sum[blockIdx.x];
    if (i == 0) row_ptr[N] = E;
}

// atomic-free bucket fill; replica id recomputed (same grid shape as hist)
__global__ void fill_csr2(const int* __restrict__ src, const int* __restrict__ dst,
                          const int* __restrict__ rank,
                          const int* __restrict__ row_ptr,
                          const int* __restrict__ cnt8,   // now replica bases
                          int* __restrict__ srcs, int E, int N)
{
    int e = blockIdx.x * 256 + threadIdx.x;
    if (e < E) {
        int d = dst[e];
        int r = blockIdx.x & (NREP - 1);
        srcs[row_ptr[d] + cnt8[(size_t)r * N + d] + rank[e]] = src[e];
    }
}

// --------------------------- pull kernels ----------------------------------
// one wave per node. lane = (half, col): half = edge-of-pair, col = uint2 col.
// Per VMEM instr: 2 rows x 256B. Main loop = 8 edges (4 paired loads in flight).
__global__ __launch_bounds__(256) void pull_h128(const uint2* __restrict__ xh4,
                                                 const int* __restrict__ row_ptr,
                                                 const int* __restrict__ srcs,
                                                 uint2* __restrict__ aggh4, int N)
{
    const int w    = (blockIdx.x * 256 + threadIdx.x) >> 6;
    const int l    = threadIdx.x & 63;
    const int half = l >> 5;        // which edge of the pair
    const int col  = l & 31;        // uint2 col -> feats 4c..4c+3
    if (w >= N) return;
    const int beg = row_ptr[w], end = row_ptr[w + 1];
    float a0 = 0.f, a1 = 0.f, a2 = 0.f, a3 = 0.f;
    int j = beg;
    for (; j + 7 < end; j += 8) {
        int s0 = srcs[j + 0 + half], s1 = srcs[j + 2 + half];
        int s2 = srcs[j + 4 + half], s3 = srcs[j + 6 + half];
        uint2 u0 = xh4[(size_t)s0 * 32 + col];
        uint2 u1 = xh4[(size_t)s1 * 32 + col];
        uint2 u2 = xh4[(size_t)s2 * 32 + col];
        uint2 u3 = xh4[(size_t)s3 * 32 + col];
        float2 p;
        p = h2f(u0.x); a0 += p.x; a1 += p.y;  p = h2f(u0.y); a2 += p.x; a3 += p.y;
        p = h2f(u1.x); a0 += p.x; a1 += p.y;  p = h2f(u1.y); a2 += p.x; a3 += p.y;
        p = h2f(u2.x); a0 += p.x; a1 += p.y;  p = h2f(u2.y); a2 += p.x; a3 += p.y;
        p = h2f(u3.x); a0 += p.x; a1 += p.y;  p = h2f(u3.y); a2 += p.x; a3 += p.y;
    }
    for (; j < end; j += 2) {                      // paired tail, predicated
        int jj = j + half;
        float m = (jj < end) ? 1.f : 0.f;
        int s = srcs[(jj < end) ? jj : (end - 1)];
        uint2 u = xh4[(size_t)s * 32 + col];
        float2 p;
        p = h2f(u.x); a0 += m * p.x; a1 += m * p.y;
        p = h2f(u.y); a2 += m * p.x; a3 += m * p.y;
    }
    // combine the two halves
    a0 += __shfl_xor(a0, 32); a1 += __shfl_xor(a1, 32);
    a2 += __shfl_xor(a2, 32); a3 += __shfl_xor(a3, 32);
    if (half == 0) {
        uint2 o; o.x = f2h(a0, a1); o.y = f2h(a2, a3);
        aggh4[(size_t)w * 32 + col] = o;
    }
}

// one wave per node. lane = (q, col): q = edge-of-quad, col = uint2 col (16/row).
// Per VMEM instr: 4 rows x 128B. Main loop = 8 edges (2 quad loads in flight).
__global__ __launch_bounds__(256) void pull_add_h64(const uint2* __restrict__ hr4,
                                                    const int* __restrict__ row_ptr,
                                                    const int* __restrict__ srcs,
                                                    float* __restrict__ out, int N)
{
    const int w   = (blockIdx.x * 256 + threadIdx.x) >> 6;
    const int l   = threadIdx.x & 63;
    const int q   = l >> 4;         // which edge of the quad
    const int col = l & 15;         // uint2 col -> feats 4c..4c+3
    if (w >= N) return;
    const int beg = row_ptr[w], end = row_ptr[w + 1];
    float a0 = 0.f, a1 = 0.f, a2 = 0.f, a3 = 0.f;
    int j = beg;
    for (; j + 7 < end; j += 8) {
        int s0 = srcs[j + q], s1 = srcs[j + 4 + q];
        uint2 u0 = hr4[(size_t)s0 * 16 + col];
        uint2 u1 = hr4[(size_t)s1 * 16 + col];
        float2 p;
        p = h2f(u0.x); a0 += p.x; a1 += p.y;  p = h2f(u0.y); a2 += p.x; a3 += p.y;
        p = h2f(u1.x); a0 += p.x; a1 += p.y;  p = h2f(u1.y); a2 += p.x; a3 += p.y;
    }
    for (; j < end; j += 4) {                      // quad tail, predicated
        int jj = j + q;
        float m = (jj < end) ? 1.f : 0.f;
        int s = srcs[(jj < end) ? jj : (end - 1)];
        uint2 u = hr4[(size_t)s * 16 + col];
        float2 p;
        p = h2f(u.x); a0 += m * p.x; a1 += m * p.y;
        p = h2f(u.y); a2 += m * p.x; a3 += m * p.y;
    }
    // combine the four quads
    a0 += __shfl_xor(a0, 16); a1 += __shfl_xor(a1, 16);
    a2 += __shfl_xor(a2, 16); a3 += __shfl_xor(a3, 16);
    a0 += __shfl_xor(a0, 32); a1 += __shfl_xor(a1, 32);
    a2 += __shfl_xor(a2, 32); a3 += __shfl_xor(a3, 32);
    if (q == 0) {
        f4* po = (f4*)out + (size_t)w * 16 + col;
        f4 cur = *po;
        cur[0] += a0; cur[1] += a1; cur[2] += a2; cur[3] += a3;
        *po = cur;
    }
}

// ----------------------- MFMA GEMM 1 (K=256 dual) --------------------------
// h = relu([aggh|xh] @ [Wr1|Wq1]^T + b1). 4 waves/block, 32 rows/wave,
// full 128 output cols per wave. acc f4[2][8]; frags direct from global.
__global__ __launch_bounds__(256) void mfma_gemm1(
    const _Float16* __restrict__ aggh, const _Float16* __restrict__ xh,
    const _Float16* __restrict__ wb,   // wr1h @0, wq1h @16384
    const float* __restrict__ b1,
    _Float16* __restrict__ h, int N)
{
    const int w  = threadIdx.x >> 6;
    const int l  = threadIdx.x & 63;
    const int lr = l & 15;
    const int kg = l >> 4;
    const int base = blockIdx.x * 128 + w * 32;
    const int r0 = min(base + lr,      N - 1);
    const int r1 = min(base + 16 + lr, N - 1);

    f4 acc[2][8];
#pragma unroll
    for (int s = 0; s < 2; ++s)
#pragma unroll
        for (int n = 0; n < 8; ++n) acc[s][n] = 0.f;

#pragma unroll 1
    for (int kk = 0; kk < 8; ++kk) {
        const _Float16* A = (kk < 4) ? aggh : xh;
        const _Float16* B = (kk < 4) ? wb : (wb + 16384);
        const int k0 = (kk & 3) * 32 + kg * 8;
        h8 a0 = *(const h8*)(A + (size_t)r0 * 128 + k0);
        h8 a1 = *(const h8*)(A + (size_t)r1 * 128 + k0);
#pragma unroll
        for (int n = 0; n < 8; ++n) {
            h8 bf = *(const h8*)(B + (size_t)(n * 16 + lr) * 128 + k0);
            acc[0][n] = __builtin_amdgcn_mfma_f32_16x16x32_f16(a0, bf, acc[0][n], 0, 0, 0);
            acc[1][n] = __builtin_amdgcn_mfma_f32_16x16x32_f16(a1, bf, acc[1][n], 0, 0, 0);
        }
    }

    const int ro = kg * 4;   // D: row = (l>>4)*4 + j, col = l&15
#pragma unroll
    for (int s = 0; s < 2; ++s)
#pragma unroll
        for (int n = 0; n < 8; ++n) {
            const int col = n * 16 + lr;
            const float bias = b1[col];
#pragma unroll
            for (int j = 0; j < 4; ++j) {
                int r = base + s * 16 + ro + j;
                if (r < N)
                    h[(size_t)r * 128 + col] = (_Float16)fmaxf(acc[s][n][j] + bias, 0.f);
            }
        }
}

// ----------------------- MFMA GEMM 2 (K=128 split) -------------------------
// cols 0..63 -> hr(f16) = h@Wr2^T ; cols 64..127 -> out(f32) = h@Wq2^T + b2
__global__ __launch_bounds__(256) void mfma_gemm2(
    const _Float16* __restrict__ h,
    const _Float16* __restrict__ wb2,  // wr2h @0, wq2h @8192 (contiguous 128x128)
    const float* __restrict__ b2,
    _Float16* __restrict__ hrh, float* __restrict__ outp, int N)
{
    const int w  = threadIdx.x >> 6;
    const int l  = threadIdx.x & 63;
    const int lr = l & 15;
    const int kg = l >> 4;
    const int base = blockIdx.x * 128 + w * 32;
    const int r0 = min(base + lr,      N - 1);
    const int r1 = min(base + 16 + lr, N - 1);

    f4 acc[2][8];
#pragma unroll
    for (int s = 0; s < 2; ++s)
#pragma unroll
        for (int n = 0; n < 8; ++n) acc[s][n] = 0.f;

#pragma unroll 1
    for (int kk = 0; kk < 4; ++kk) {
        const int k0 = kk * 32 + kg * 8;
        h8 a0 = *(const h8*)(h + (size_t)r0 * 128 + k0);
        h8 a1 = *(const h8*)(h + (size_t)r1 * 128 + k0);
#pragma unroll
        for (int n = 0; n < 8; ++n) {
            h8 bf = *(const h8*)(wb2 + (size_t)(n * 16 + lr) * 128 + k0);
            acc[0][n] = __builtin_amdgcn_mfma_f32_16x16x32_f16(a0, bf, acc[0][n], 0, 0, 0);
            acc[1][n] = __builtin_amdgcn_mfma_f32_16x16x32_f16(a1, bf, acc[1][n], 0, 0, 0);
        }
    }

    const int ro = kg * 4;
#pragma unroll
    for (int s = 0; s < 2; ++s)
#pragma unroll
        for (int n = 0; n < 8; ++n) {
            const int col = n * 16 + lr;
#pragma unroll
            for (int j = 0; j < 4; ++j) {
                int r = base + s * 16 + ro + j;
                if (r < N) {
                    if (n < 4) {
                        hrh[(size_t)r * 64 + col] = (_Float16)acc[s][n][j];
                    } else {
                        outp[(size_t)r * 64 + (col - 64)] = acc[s][n][j] + b2[col - 64];
                    }
                }
            }
        }
}

extern "C" void kernel_launch(void* const* d_in, const int* in_sizes, int n_in,
                              void* d_out, int out_size, void* d_ws, size_t ws_size,
                              hipStream_t stream)
{
    const float* x       = (const float*)d_in[0];
    const int*   ei      = (const int*)d_in[1];
    const float* w_rel1  = (const float*)d_in[2];
    const float* b_rel1  = (const float*)d_in[3];
    const float* w_root1 = (const float*)d_in[4];
    const float* w_rel2  = (const float*)d_in[5];
    const float* b_rel2  = (const float*)d_in[6];
    const float* w_root2 = (const float*)d_in[7];
    float* out = (float*)d_out;

    const int N = in_sizes[0] / 128;
    const int E = in_sizes[1] / 2;
    const int* src = ei;        // edge_index[0]
    const int* dst = ei + E;    // edge_index[1]

    // workspace (~93 MB), all f16 tensors [row][feat]:
    //   xh [N*128] | aggh [N*128] (hr aliases it) | h [N*128] | wbuf [49152]
    //   | srcs [E] | rank [E] | row_ptr [N+1] | cnt8 [8*N] | blk_sum [1024]
    _Float16* xh    = (_Float16*)d_ws;
    _Float16* aggh  = xh + (size_t)N * 128;
    _Float16* hbuf  = aggh + (size_t)N * 128;
    _Float16* hrh   = aggh;                         // alias: aggh dead after gemm1
    _Float16* wbuf  = hbuf + (size_t)N * 128;
    int*      srcs    = (int*)(wbuf + 49152);
    int*      rank    = srcs + E;
    int*      row_ptr = rank + E;
    int*      cnt8    = row_ptr + (N + 1);          // NREP*N ints (3.2 MB)
    int*      blk_sum = cnt8 + (size_t)NREP * N;

    const int nb = (N + 255) / 256;
    const int egrid = (E + 255) / 256;

    // ---- f16 staging ----
    wcast<<<(49152 + 255) / 256, 256, 0, stream>>>(w_rel1, w_root1, w_rel2, w_root2, wbuf);
    xcast<<<(N * 128 / 8 + 255) / 256, 256, 0, stream>>>(x, xh, (long)N * 128);

    // ---- CSR build (shared by both layers) ----
    hipMemsetAsync(cnt8, 0, (size_t)NREP * N * sizeof(int), stream);
    hist_rank<<<egrid, 256, 0, stream>>>(dst, cnt8, rank, E, N);
    scan_p1<<<nb, 256, 0, stream>>>(cnt8, row_ptr, blk_sum, N);
    scan_p2<<<1, 1024, 0, stream>>>(blk_sum, nb);
    scan_p3<<<nb, 256, 0, stream>>>(row_ptr, blk_sum, N, E);
    fill_csr2<<<egrid, 256, 0, stream>>>(src, dst, rank, row_ptr, cnt8, srcs, E, N);

    // 1. aggh = pull-sum xh
    pull_h128<<<(N * 64 + 255) / 256, 256, 0, stream>>>(
        (const uint2*)xh, row_ptr, srcs, (uint2*)aggh, N);

    // 2/3. MFMA GEMMs
    {
        int grid = (N + 127) / 128;
        mfma_gemm1<<<grid, 256, 0, stream>>>(aggh, xh, wbuf, b_rel1, hbuf, N);
        mfma_gemm2<<<grid, 256, 0, stream>>>(hbuf, wbuf + 32768, b_rel2, hrh, out, N);
    }

    // 4. out += pull-sum hr
    pull_add_h64<<<(N * 64 + 255) / 256, 256, 0, stream>>>(
        (const uint2*)hrh, row_ptr, srcs, out, N);
}

// Round 11
// 260.657 us; speedup vs baseline: 1.2084x; 1.2084x over previous
//
#include <hip/hip_runtime.h>

// GraphConv x2, CSR-pull + f16 MFMA GEMMs (R11):
//   wcast/xcast -> f16 staging
//   CSR build: ATOMIC-FREE 2-level counting sort by dst
//     s1: per-block LDS hist over 1024 coarse buckets (dst>>7) -> mat
//     s2: per-bucket column scan of mat ; s2b: bucket_base scan
//     s3: scatter packed (src<<7|dst&127) into coarse[] via LDS cursors
//     s4: per-bucket fine 128-bin hist+scan -> row_ptr + srcs[]
//   pull_h128 / mfma_gemm1 / mfma_gemm2 / pull_add_h64 unchanged from R9.
//
// R11 rationale: R10's replica theory FAILED (hist_rank 63us, WRITE 56MB
// unchanged). 56MB = 1.6M atomics x 32B write-through: device-scope returning
// atomics execute at the memory-side coherence point (~12.7/cy device-wide
// HW floor) — no layout helps. This build has ZERO global atomics: LDS
// atomics + dense scans + plain stores only.

typedef float f4 __attribute__((ext_vector_type(4)));
typedef _Float16 h8 __attribute__((ext_vector_type(8)));
typedef _Float16 h2 __attribute__((ext_vector_type(2)));

#define NB   1024    // coarse buckets (dst>>7); requires N <= 131072
#define EPB  4096    // edges per block in s1/s3; nblk = ceil(E/EPB) <= 512

__device__ __forceinline__ float2 h2f(unsigned u) {
    h2 p = __builtin_bit_cast(h2, u);
    float2 r; r.x = (float)p[0]; r.y = (float)p[1];
    return r;
}
__device__ __forceinline__ unsigned f2h(float a, float b) {
    h2 p; p[0] = (_Float16)a; p[1] = (_Float16)b;
    return __builtin_bit_cast(unsigned, p);
}

// ---------------------------- casts ----------------------------------------
// wbuf layout (halves): wr1h @0 [128x128] | wq1h @16384 | wr2h @32768 [64x128]
// | wq2h @40960  (total 49152)
__global__ void wcast(const float* __restrict__ wr1, const float* __restrict__ wq1,
                      const float* __restrict__ wr2, const float* __restrict__ wq2,
                      _Float16* __restrict__ wb)
{
    int i = blockIdx.x * 256 + threadIdx.x;
    if (i < 16384)      wb[i] = (_Float16)wr1[i];
    else if (i < 32768) wb[i] = (_Float16)wq1[i - 16384];
    else if (i < 40960) wb[i] = (_Float16)wr2[i - 32768];
    else if (i < 49152) wb[i] = (_Float16)wq2[i - 40960];
}

__global__ void xcast(const float* __restrict__ x, _Float16* __restrict__ xh,
                      long n)   // n = N*128, multiple of 8
{
    long i = (long)(blockIdx.x * 256 + threadIdx.x) * 8;
    if (i >= n) return;
    f4 a = *(const f4*)(x + i);
    f4 b = *(const f4*)(x + i + 4);
    h8 o;
    o[0] = (_Float16)a[0]; o[1] = (_Float16)a[1];
    o[2] = (_Float16)a[2]; o[3] = (_Float16)a[3];
    o[4] = (_Float16)b[0]; o[5] = (_Float16)b[1];
    o[6] = (_Float16)b[2]; o[7] = (_Float16)b[3];
    *(h8*)(xh + i) = o;
}

// ------------------ CSR build: atomic-free counting sort --------------------
// s1: per-block coarse histogram (LDS) -> mat[blk][NB]
__global__ __launch_bounds__(256) void s1_hist(const int* __restrict__ dst,
                                               int* __restrict__ mat, int E)
{
    __shared__ int hist[NB];
    const int tid = threadIdx.x;
    for (int i = tid; i < NB; i += 256) hist[i] = 0;
    __syncthreads();
    const int e0 = blockIdx.x * EPB;
#pragma unroll
    for (int it = 0; it < EPB / 256; ++it) {
        int e = e0 + it * 256 + tid;
        if (e < E) atomicAdd(&hist[dst[e] >> 7], 1);
    }
    __syncthreads();
    int* row = mat + (size_t)blockIdx.x * NB;
    for (int i = tid; i < NB; i += 256) row[i] = hist[i];
}

// s2: one block per bucket; exclusive scan down the column (nblk <= 512);
// mat[k][b] <- exclusive prefix; tot[b] = column total
__global__ __launch_bounds__(512) void s2_colscan(int* __restrict__ mat,
                                                  int* __restrict__ tot, int nblk)
{
    __shared__ int ts[512];
    const int tid = threadIdx.x;
    const int b = blockIdx.x;
    int v = (tid < nblk) ? mat[(size_t)tid * NB + b] : 0;
    ts[tid] = v;
    __syncthreads();
#pragma unroll
    for (int off = 1; off < 512; off <<= 1) {
        int add = (tid >= off) ? ts[tid - off] : 0;
        __syncthreads();
        ts[tid] += add;
        __syncthreads();
    }
    if (tid < nblk) mat[(size_t)tid * NB + b] = ts[tid] - v;
    if (tid == 511) tot[b] = ts[511];
}

// s2b: exclusive scan of NB bucket totals -> bb[0..NB]; row_ptr[N] = E
__global__ __launch_bounds__(NB) void s2b_base(const int* __restrict__ tot,
                                               int* __restrict__ bb,
                                               int* __restrict__ row_ptr,
                                               int N, int E)
{
    __shared__ int ts[NB];
    const int tid = threadIdx.x;
    int v = tot[tid];
    ts[tid] = v;
    __syncthreads();
#pragma unroll
    for (int off = 1; off < NB; off <<= 1) {
        int add = (tid >= off) ? ts[tid - off] : 0;
        __syncthreads();
        ts[tid] += add;
        __syncthreads();
    }
    bb[tid] = ts[tid] - v;
    if (tid == NB - 1) { bb[NB] = ts[NB - 1]; row_ptr[N] = E; }
}

// s3: coarse scatter; cursor[b] = bb[b] + mat[blk][b]; LDS-atomic local rank;
// coarse[p] = (src<<7) | (dst&127)   [24-bit pack, needs N <= 2^17]
__global__ __launch_bounds__(256) void s3_scatter(const int* __restrict__ src,
                                                  const int* __restrict__ dst,
                                                  const int* __restrict__ mat,
                                                  const int* __restrict__ bb,
                                                  unsigned* __restrict__ coarse, int E)
{
    __shared__ int cur[NB];
    const int tid = threadIdx.x;
    const int* mrow = mat + (size_t)blockIdx.x * NB;
    for (int i = tid; i < NB; i += 256) cur[i] = bb[i] + mrow[i];
    __syncthreads();
    const int e0 = blockIdx.x * EPB;
#pragma unroll
    for (int it = 0; it < EPB / 256; ++it) {
        int e = e0 + it * 256 + tid;
        if (e < E) {
            int d = dst[e];
            int p = atomicAdd(&cur[d >> 7], 1);
            coarse[p] = ((unsigned)src[e] << 7) | (unsigned)(d & 127);
        }
    }
}

// s4: one block per bucket; fine 128-bin hist+scan -> row_ptr + final srcs[]
__global__ __launch_bounds__(256) void s4_fine(const unsigned* __restrict__ coarse,
                                               const int* __restrict__ bb,
                                               int* __restrict__ row_ptr,
                                               int* __restrict__ srcs, int N)
{
    __shared__ int fcnt[128];
    __shared__ int fs[128];
    __shared__ int cur[128];
    const int tid = threadIdx.x;
    const int b = blockIdx.x;
    const int seg0 = bb[b], seg1 = bb[b + 1];
    if (tid < 128) fcnt[tid] = 0;
    __syncthreads();
    for (int p = seg0 + tid; p < seg1; p += 256)
        atomicAdd(&fcnt[coarse[p] & 127u], 1);
    __syncthreads();
    if (tid < 128) fs[tid] = fcnt[tid];
    __syncthreads();
#pragma unroll
    for (int off = 1; off < 128; off <<= 1) {
        int add = 0;
        if (tid < 128 && tid >= off) add = fs[tid - off];
        __syncthreads();
        if (tid < 128) fs[tid] += add;
        __syncthreads();
    }
    if (tid < 128) {
        int excl = fs[tid] - fcnt[tid];
        cur[tid] = seg0 + excl;
        int d = b * 128 + tid;
        if (d < N) row_ptr[d] = seg0 + excl;
    }
    __syncthreads();
    for (int p = seg0 + tid; p < seg1; p += 256) {
        unsigned v = coarse[p];
        int q = atomicAdd(&cur[v & 127u], 1);
        srcs[q] = (int)(v >> 7);
    }
}

// --------------------------- pull kernels ----------------------------------
// one wave per node. lane = (half, col): half = edge-of-pair, col = uint2 col.
// Per VMEM instr: 2 rows x 256B. Main loop = 8 edges (4 paired loads in flight).
__global__ __launch_bounds__(256) void pull_h128(const uint2* __restrict__ xh4,
                                                 const int* __restrict__ row_ptr,
                                                 const int* __restrict__ srcs,
                                                 uint2* __restrict__ aggh4, int N)
{
    const int w    = (blockIdx.x * 256 + threadIdx.x) >> 6;
    const int l    = threadIdx.x & 63;
    const int half = l >> 5;        // which edge of the pair
    const int col  = l & 31;        // uint2 col -> feats 4c..4c+3
    if (w >= N) return;
    const int beg = row_ptr[w], end = row_ptr[w + 1];
    float a0 = 0.f, a1 = 0.f, a2 = 0.f, a3 = 0.f;
    int j = beg;
    for (; j + 7 < end; j += 8) {
        int s0 = srcs[j + 0 + half], s1 = srcs[j + 2 + half];
        int s2 = srcs[j + 4 + half], s3 = srcs[j + 6 + half];
        uint2 u0 = xh4[(size_t)s0 * 32 + col];
        uint2 u1 = xh4[(size_t)s1 * 32 + col];
        uint2 u2 = xh4[(size_t)s2 * 32 + col];
        uint2 u3 = xh4[(size_t)s3 * 32 + col];
        float2 p;
        p = h2f(u0.x); a0 += p.x; a1 += p.y;  p = h2f(u0.y); a2 += p.x; a3 += p.y;
        p = h2f(u1.x); a0 += p.x; a1 += p.y;  p = h2f(u1.y); a2 += p.x; a3 += p.y;
        p = h2f(u2.x); a0 += p.x; a1 += p.y;  p = h2f(u2.y); a2 += p.x; a3 += p.y;
        p = h2f(u3.x); a0 += p.x; a1 += p.y;  p = h2f(u3.y); a2 += p.x; a3 += p.y;
    }
    for (; j < end; j += 2) {                      // paired tail, predicated
        int jj = j + half;
        float m = (jj < end) ? 1.f : 0.f;
        int s = srcs[(jj < end) ? jj : (end - 1)];
        uint2 u = xh4[(size_t)s * 32 + col];
        float2 p;
        p = h2f(u.x); a0 += m * p.x; a1 += m * p.y;
        p = h2f(u.y); a2 += m * p.x; a3 += m * p.y;
    }
    // combine the two halves
    a0 += __shfl_xor(a0, 32); a1 += __shfl_xor(a1, 32);
    a2 += __shfl_xor(a2, 32); a3 += __shfl_xor(a3, 32);
    if (half == 0) {
        uint2 o; o.x = f2h(a0, a1); o.y = f2h(a2, a3);
        aggh4[(size_t)w * 32 + col] = o;
    }
}

// one wave per node. lane = (q, col): q = edge-of-quad, col = uint2 col (16/row).
// Per VMEM instr: 4 rows x 128B. Main loop = 8 edges (2 quad loads in flight).
__global__ __launch_bounds__(256) void pull_add_h64(const uint2* __restrict__ hr4,
                                                    const int* __restrict__ row_ptr,
                                                    const int* __restrict__ srcs,
                                                    float* __restrict__ out, int N)
{
    const int w   = (blockIdx.x * 256 + threadIdx.x) >> 6;
    const int l   = threadIdx.x & 63;
    const int q   = l >> 4;         // which edge of the quad
    const int col = l & 15;         // uint2 col -> feats 4c..4c+3
    if (w >= N) return;
    const int beg = row_ptr[w], end = row_ptr[w + 1];
    float a0 = 0.f, a1 = 0.f, a2 = 0.f, a3 = 0.f;
    int j = beg;
    for (; j + 7 < end; j += 8) {
        int s0 = srcs[j + q], s1 = srcs[j + 4 + q];
        uint2 u0 = hr4[(size_t)s0 * 16 + col];
        uint2 u1 = hr4[(size_t)s1 * 16 + col];
        float2 p;
        p = h2f(u0.x); a0 += p.x; a1 += p.y;  p = h2f(u0.y); a2 += p.x; a3 += p.y;
        p = h2f(u1.x); a0 += p.x; a1 += p.y;  p = h2f(u1.y); a2 += p.x; a3 += p.y;
    }
    for (; j < end; j += 4) {                      // quad tail, predicated
        int jj = j + q;
        float m = (jj < end) ? 1.f : 0.f;
        int s = srcs[(jj < end) ? jj : (end - 1)];
        uint2 u = hr4[(size_t)s * 16 + col];
        float2 p;
        p = h2f(u.x); a0 += m * p.x; a1 += m * p.y;
        p = h2f(u.y); a2 += m * p.x; a3 += m * p.y;
    }
    // combine the four quads
    a0 += __shfl_xor(a0, 16); a1 += __shfl_xor(a1, 16);
    a2 += __shfl_xor(a2, 16); a3 += __shfl_xor(a3, 16);
    a0 += __shfl_xor(a0, 32); a1 += __shfl_xor(a1, 32);
    a2 += __shfl_xor(a2, 32); a3 += __shfl_xor(a3, 32);
    if (q == 0) {
        f4* po = (f4*)out + (size_t)w * 16 + col;
        f4 cur = *po;
        cur[0] += a0; cur[1] += a1; cur[2] += a2; cur[3] += a3;
        *po = cur;
    }
}

// ----------------------- MFMA GEMM 1 (K=256 dual) --------------------------
// h = relu([aggh|xh] @ [Wr1|Wq1]^T + b1). 4 waves/block, 32 rows/wave,
// full 128 output cols per wave. acc f4[2][8]; frags direct from global.
__global__ __launch_bounds__(256) void mfma_gemm1(
    const _Float16* __restrict__ aggh, const _Float16* __restrict__ xh,
    const _Float16* __restrict__ wb,   // wr1h @0, wq1h @16384
    const float* __restrict__ b1,
    _Float16* __restrict__ h, int N)
{
    const int w  = threadIdx.x >> 6;
    const int l  = threadIdx.x & 63;
    const int lr = l & 15;
    const int kg = l >> 4;
    const int base = blockIdx.x * 128 + w * 32;
    const int r0 = min(base + lr,      N - 1);
    const int r1 = min(base + 16 + lr, N - 1);

    f4 acc[2][8];
#pragma unroll
    for (int s = 0; s < 2; ++s)
#pragma unroll
        for (int n = 0; n < 8; ++n) acc[s][n] = 0.f;

#pragma unroll 1
    for (int kk = 0; kk < 8; ++kk) {
        const _Float16* A = (kk < 4) ? aggh : xh;
        const _Float16* B = (kk < 4) ? wb : (wb + 16384);
        const int k0 = (kk & 3) * 32 + kg * 8;
        h8 a0 = *(const h8*)(A + (size_t)r0 * 128 + k0);
        h8 a1 = *(const h8*)(A + (size_t)r1 * 128 + k0);
#pragma unroll
        for (int n = 0; n < 8; ++n) {
            h8 bf = *(const h8*)(B + (size_t)(n * 16 + lr) * 128 + k0);
            acc[0][n] = __builtin_amdgcn_mfma_f32_16x16x32_f16(a0, bf, acc[0][n], 0, 0, 0);
            acc[1][n] = __builtin_amdgcn_mfma_f32_16x16x32_f16(a1, bf, acc[1][n], 0, 0, 0);
        }
    }

    const int ro = kg * 4;   // D: row = (l>>4)*4 + j, col = l&15
#pragma unroll
    for (int s = 0; s < 2; ++s)
#pragma unroll
        for (int n = 0; n < 8; ++n) {
            const int col = n * 16 + lr;
            const float bias = b1[col];
#pragma unroll
            for (int j = 0; j < 4; ++j) {
                int r = base + s * 16 + ro + j;
                if (r < N)
                    h[(size_t)r * 128 + col] = (_Float16)fmaxf(acc[s][n][j] + bias, 0.f);
            }
        }
}

// ----------------------- MFMA GEMM 2 (K=128 split) -------------------------
// cols 0..63 -> hr(f16) = h@Wr2^T ; cols 64..127 -> out(f32) = h@Wq2^T + b2
__global__ __launch_bounds__(256) void mfma_gemm2(
    const _Float16* __restrict__ h,
    const _Float16* __restrict__ wb2,  // wr2h @0, wq2h @8192 (contiguous 128x128)
    const float* __restrict__ b2,
    _Float16* __restrict__ hrh, float* __restrict__ outp, int N)
{
    const int w  = threadIdx.x >> 6;
    const int l  = threadIdx.x & 63;
    const int lr = l & 15;
    const int kg = l >> 4;
    const int base = blockIdx.x * 128 + w * 32;
    const int r0 = min(base + lr,      N - 1);
    const int r1 = min(base + 16 + lr, N - 1);

    f4 acc[2][8];
#pragma unroll
    for (int s = 0; s < 2; ++s)
#pragma unroll
        for (int n = 0; n < 8; ++n) acc[s][n] = 0.f;

#pragma unroll 1
    for (int kk = 0; kk < 4; ++kk) {
        const int k0 = kk * 32 + kg * 8;
        h8 a0 = *(const h8*)(h + (size_t)r0 * 128 + k0);
        h8 a1 = *(const h8*)(h + (size_t)r1 * 128 + k0);
#pragma unroll
        for (int n = 0; n < 8; ++n) {
            h8 bf = *(const h8*)(wb2 + (size_t)(n * 16 + lr) * 128 + k0);
            acc[0][n] = __builtin_amdgcn_mfma_f32_16x16x32_f16(a0, bf, acc[0][n], 0, 0, 0);
            acc[1][n] = __builtin_amdgcn_mfma_f32_16x16x32_f16(a1, bf, acc[1][n], 0, 0, 0);
        }
    }

    const int ro = kg * 4;
#pragma unroll
    for (int s = 0; s < 2; ++s)
#pragma unroll
        for (int n = 0; n < 8; ++n) {
            const int col = n * 16 + lr;
#pragma unroll
            for (int j = 0; j < 4; ++j) {
                int r = base + s * 16 + ro + j;
                if (r < N) {
                    if (n < 4) {
                        hrh[(size_t)r * 64 + col] = (_Float16)acc[s][n][j];
                    } else {
                        outp[(size_t)r * 64 + (col - 64)] = acc[s][n][j] + b2[col - 64];
                    }
                }
            }
        }
}

extern "C" void kernel_launch(void* const* d_in, const int* in_sizes, int n_in,
                              void* d_out, int out_size, void* d_ws, size_t ws_size,
                              hipStream_t stream)
{
    const float* x       = (const float*)d_in[0];
    const int*   ei      = (const int*)d_in[1];
    const float* w_rel1  = (const float*)d_in[2];
    const float* b_rel1  = (const float*)d_in[3];
    const float* w_root1 = (const float*)d_in[4];
    const float* w_rel2  = (const float*)d_in[5];
    const float* b_rel2  = (const float*)d_in[6];
    const float* w_root2 = (const float*)d_in[7];
    float* out = (float*)d_out;

    const int N = in_sizes[0] / 128;
    const int E = in_sizes[1] / 2;
    const int* src = ei;        // edge_index[0]
    const int* dst = ei + E;    // edge_index[1]

    // workspace (~92 MB):
    //   xh [N*128 h] | aggh [N*128 h] (hrh aliases) | hbuf [N*128 h]
    //   | wbuf [49152 h] | srcs [E] | coarse [E u32] | mat [nblk*NB]
    //   | tot [NB] | bb [NB+1] | row_ptr [N+1]
    _Float16* xh    = (_Float16*)d_ws;
    _Float16* aggh  = xh + (size_t)N * 128;
    _Float16* hbuf  = aggh + (size_t)N * 128;
    _Float16* hrh   = aggh;                         // alias: aggh dead after gemm1
    _Float16* wbuf  = hbuf + (size_t)N * 128;
    int*      srcs    = (int*)(wbuf + 49152);
    unsigned* coarse  = (unsigned*)(srcs + E);
    const int nblk    = (E + EPB - 1) / EPB;        // <= 512 (E <= 2M)
    int*      mat     = (int*)(coarse + E);         // nblk*NB
    int*      tot     = mat + (size_t)nblk * NB;    // NB
    int*      bb      = tot + NB;                   // NB+1
    int*      row_ptr = bb + (NB + 1);              // N+1

    // ---- f16 staging ----
    wcast<<<(49152 + 255) / 256, 256, 0, stream>>>(w_rel1, w_root1, w_rel2, w_root2, wbuf);
    xcast<<<(N * 128 / 8 + 255) / 256, 256, 0, stream>>>(x, xh, (long)N * 128);

    // ---- CSR build: atomic-free 2-level counting sort ----
    s1_hist   <<<nblk, 256, 0, stream>>>(dst, mat, E);
    s2_colscan<<<NB, 512, 0, stream>>>(mat, tot, nblk);
    s2b_base  <<<1, NB, 0, stream>>>(tot, bb, row_ptr, N, E);
    s3_scatter<<<nblk, 256, 0, stream>>>(src, dst, mat, bb, coarse, E);
    s4_fine   <<<NB, 256, 0, stream>>>(coarse, bb, row_ptr, srcs, N);

    // 1. aggh = pull-sum xh
    pull_h128<<<(N * 64 + 255) / 256, 256, 0, stream>>>(
        (const uint2*)xh, row_ptr, srcs, (uint2*)aggh, N);

    // 2/3. MFMA GEMMs
    {
        int grid = (N + 127) / 128;
        mfma_gemm1<<<grid, 256, 0, stream>>>(aggh, xh, wbuf, b_rel1, hbuf, N);
        mfma_gemm2<<<grid, 256, 0, stream>>>(hbuf, wbuf + 32768, b_rel2, hrh, out, N);
    }

    // 4. out += pull-sum hr
    pull_add_h64<<<(N * 64 + 255) / 256, 256, 0, stream>>>(
        (const uint2*)hrh, row_ptr, srcs, out, N);
}